// Round 11
// baseline (312.623 us; speedup 1.0000x reference)
//
#include <hip/hip_runtime.h>
#include <math.h>

#define LSZ 128
#define NCH 8
#define NLAY 16
#define LOG2E 1.4426950408889634f
#define LN2   0.6931471805599453f

typedef float f4 __attribute__((ext_vector_type(4)));
typedef float f2 __attribute__((ext_vector_type(2)));

// wave-uniform float -> SGPR
__device__ __forceinline__ float uni(float v) {
    return __uint_as_float(__builtin_amdgcn_readfirstlane(__float_as_uint(v)));
}

// unpack 4 bf16 (one ds_read_b64) -> f4.  bf16->f32 is exact (<<16).
__device__ __forceinline__ f4 unpk(uint2 w) {
    f4 r;
    r.x = __uint_as_float(w.x << 16);
    r.y = __uint_as_float(w.x & 0xffff0000u);
    r.z = __uint_as_float(w.y << 16);
    r.w = __uint_as_float(w.y & 0xffff0000u);
    return r;
}
__device__ __forceinline__ f4 ldsq(const unsigned short* p) {
    return unpk(*(const uint2*)p);
}
// pack f4 -> 4 bf16 with RNE (v_cvt_pk_bf16_f32), one ds_write_b64.
__device__ __forceinline__ void stsq(unsigned short* p, f4 v) {
    unsigned lo, hi;
    asm("v_cvt_pk_bf16_f32 %0, %1, %2" : "=v"(lo) : "v"(v.x), "v"(v.y));
    asm("v_cvt_pk_bf16_f32 %0, %1, %2" : "=v"(hi) : "v"(v.z), "v"(v.w));
    *(uint2*)p = make_uint2(lo, hi);
}

// One block per (batch, channel) plane. 1024 threads: 32 row-strips x 32
// col-groups, 4 rows x 4 cols per thread. Planes stored in LDS as BF16
// (32 KB each, ping-pong, single barrier/layer): halves the LDS-pipe bytes
// (the measured bottleneck) and halves the block's LDS footprint ->
// 2 blocks/CU (32 waves) become possible. Own rows carried in f32 registers
// (center taps exact); halo taps carry ~0.8% bf16 rounding, which averages
// out in the final mean (output err ~1e-4 << 2e-2 threshold, RNE unbiased).
// Uniform-shift fold: x = x~ - l; weights pre-scaled by log2e;
// CELU tail = fma(max(y',0), ln2, x~) + exp2(min(y',0)).
__global__ __launch_bounds__(1024)
void plane_kernel(const float* __restrict__ nrm,   // (256,128,3)
                  const float* __restrict__ W,     // (16,8,5)
                  float* __restrict__ ws)          // (2048,) per-block sums
{
    __shared__ __align__(16) unsigned short xa[LSZ * LSZ];   // 32768 B
    __shared__ __align__(16) unsigned short xb[LSZ * LSZ];   // 32768 B
    __shared__ float nsm[LSZ * 3];
    __shared__ float wsm[NLAY * 5];
    __shared__ float red[16];

    const int bid = blockIdx.x;
    const int b   = bid >> 3;
    const int c   = bid & 7;
    const int tid = threadIdx.x;

    if (tid < LSZ * 3) nsm[tid] = nrm[b * (LSZ * 3) + tid];
    if (tid < NLAY * 5) {
        int l = tid / 5, d = tid % 5;
        wsm[tid] = W[l * (NCH * 5) + c * 5 + d] * LOG2E;   // pre-scaled
    }
    __syncthreads();

    const int jg = tid & 31;        // col group  -> j0 = 4*jg
    const int is = tid >> 5;        // row strip  -> i0 = 4*is
    const int j0 = jg * 4;
    const int i0 = is * 4;

    f4 own[4];   // this thread's 4 rows (x~ state, f32, carried in registers)

    // ---- init: g[i][j] = dot3(n[i], n[j]), zero diagonal ----
    {
        float nj0x = nsm[(j0 + 0) * 3 + 0], nj0y = nsm[(j0 + 0) * 3 + 1], nj0z = nsm[(j0 + 0) * 3 + 2];
        float nj1x = nsm[(j0 + 1) * 3 + 0], nj1y = nsm[(j0 + 1) * 3 + 1], nj1z = nsm[(j0 + 1) * 3 + 2];
        float nj2x = nsm[(j0 + 2) * 3 + 0], nj2y = nsm[(j0 + 2) * 3 + 1], nj2z = nsm[(j0 + 2) * 3 + 2];
        float nj3x = nsm[(j0 + 3) * 3 + 0], nj3y = nsm[(j0 + 3) * 3 + 1], nj3z = nsm[(j0 + 3) * 3 + 2];
#pragma unroll
        for (int k = 0; k < 4; ++k) {
            int r = i0 + k;
            float n0 = nsm[r * 3 + 0], n1 = nsm[r * 3 + 1], n2 = nsm[r * 3 + 2];
            float g0 = n0 * nj0x + n1 * nj0y + n2 * nj0z;
            float g1 = n0 * nj1x + n1 * nj1y + n2 * nj1z;
            float g2 = n0 * nj2x + n1 * nj2y + n2 * nj2z;
            float g3 = n0 * nj3x + n1 * nj3y + n2 * nj3z;
            if (r == j0 + 0) g0 = 0.f;
            if (r == j0 + 1) g1 = 0.f;
            if (r == j0 + 2) g2 = 0.f;
            if (r == j0 + 3) g3 = 0.f;
            f4 v = (f4){g0, g1, g2, g3};
            stsq(&xa[r * LSZ + j0], v);
            own[k] = v;
        }
    }
    __syncthreads();

    // LDS offsets (bf16 elements). Halo strips are 4-row aligned ->
    // contiguous across the wrap; row offsets k*LSZ -> ds immediates.
    const int oT = ((i0 - 4) & (LSZ - 1)) * LSZ + j0;   // top halo strip
    const int oB = ((i0 + 4) & (LSZ - 1)) * LSZ + j0;   // bottom halo strip
    const int oL = i0 * LSZ + ((j0 - 4) & (LSZ - 1));   // left cols
    const int oR = i0 * LSZ + ((j0 + 4) & (LSZ - 1));   // right cols
    const int oO = i0 * LSZ + j0;                       // own rows

    auto do_layer = [&](const unsigned short* src, unsigned short* dst, int l) {
        const float w0 = uni(wsm[l * 5 + 0]);
        const float w1 = uni(wsm[l * 5 + 1]);
        const float w2 = uni(wsm[l * 5 + 2]);
        const float w3 = uni(wsm[l * 5 + 3]);
        const float w4 = uni(wsm[l * 5 + 4]);
        // uniform shift: entering layer l, x = x~ - l; stencil(const) = s*T
        const float sT = -(float)l * (w0 + 4.0f * (w1 + w2 + w3 + w4));

        f4 t[4], bo[4], res[4];
#pragma unroll
        for (int k = 0; k < 4; ++k) {
            t[k]  = ldsq(&src[oT + k * LSZ]);
            bo[k] = ldsq(&src[oB + k * LSZ]);
        }

        // VV(k): vertical stack rows i0-4+k, k = 0..11
#define VV(k) ((k) < 4 ? t[(k)] : (k) < 8 ? own[(k) - 4] : bo[(k) - 8])

        uint2 Lp = *(const uint2*)&src[oL];
        uint2 Rp = *(const uint2*)&src[oR];
#pragma unroll
        for (int m = 0; m < 4; ++m) {
            uint2 Lpn, Rpn;
            if (m < 3) {
                Lpn = *(const uint2*)&src[oL + (m + 1) * LSZ];
                Rpn = *(const uint2*)&src[oR + (m + 1) * LSZ];
            }
            const f4 Lc = unpk(Lp);
            const f4 Rc = unpk(Rp);
            const f4 C = own[m];

            // horizontal shifted-pair taps (pk-pair structured)
            f2 h1m = C.xy + C.zw;                      // {C.x+C.z, C.y+C.w}
            f4 h1 = (f4){Lc.w + C.y, h1m.x, h1m.y, C.z + Rc.x};
            f2 h2a = Lc.zw + C.zw;                     // {Lc.z+C.z, Lc.w+C.w}
            f2 h2b = C.xy + Rc.xy;                     // {C.x+Rc.x, C.y+Rc.y}
            f4 h2 = (f4){h2a.x, h2a.y, h2b.x, h2b.y};
            f2 h3m = Lc.zw + Rc.xy;                    // {Lc.z+Rc.x, Lc.w+Rc.y}
            f4 h3 = (f4){Lc.y + C.w, h3m.x, h3m.y, C.x + Rc.z};
            f4 h4 = Lc + Rc;

            // y' = y * log2e (weights pre-scaled); sT folds into the first fma
            f4 y = (w0 * C + sT)
                 + w1 * (h1 + (VV(m + 3) + VV(m + 5)))
                 + w2 * (h2 + (VV(m + 2) + VV(m + 6)))
                 + w3 * (h3 + (VV(m + 1) + VV(m + 7)))
                 + w4 * (h4 + (VV(m + 0) + VV(m + 8)));

            f4 yp = __builtin_elementwise_max(y, (f4)0.0f);
            f4 yn = __builtin_elementwise_min(y, (f4)0.0f);
            f4 e2;
            e2.x = __builtin_amdgcn_exp2f(yn.x);
            e2.y = __builtin_amdgcn_exp2f(yn.y);
            e2.z = __builtin_amdgcn_exp2f(yn.z);
            e2.w = __builtin_amdgcn_exp2f(yn.w);
            f4 r = (yp * LN2 + C) + e2;    // x~_next ("-1" lives in the shift)

            stsq(&dst[oO + m * LSZ], r);   // write immediately (plane B unread)
            res[m] = r;

            Lp = Lpn; Rp = Rpn;
        }
#undef VV
#pragma unroll
        for (int m = 0; m < 4; ++m) own[m] = res[m];
        __syncthreads();                   // single barrier per layer
    };

#pragma unroll 1
    for (int l = 0; l < NLAY; l += 2) {
        do_layer(xa, xb, l);
        do_layer(xb, xa, l + 1);
    }

    // ---- per-block sum of final plane (x~ in own[0..3], f32) ----
    float local = 0.f;
#pragma unroll
    for (int m = 0; m < 4; ++m)
        local += own[m].x + own[m].y + own[m].z + own[m].w;

#pragma unroll
    for (int off = 32; off > 0; off >>= 1)
        local += __shfl_down(local, off, 64);

    const int wave = tid >> 6;
    if ((tid & 63) == 0) red[wave] = local;
    __syncthreads();
    if (tid == 0) {
        float s = 0.f;
#pragma unroll
        for (int w = 0; w < 16; ++w) s += red[w];
        ws[bid] = s;
    }
}

__global__ void finish_kernel(const float* __restrict__ ws, float* __restrict__ out) {
    int b = threadIdx.x;
    float s = 0.f;
#pragma unroll
    for (int c = 0; c < NCH; ++c) s += ws[b * NCH + c];
    // x = x~ - 16 after all layers: mean_true = mean(x~) - 16
    out[b] = expf(16.0f - s / (8.0f * 128.0f * 128.0f));
}

extern "C" void kernel_launch(void* const* d_in, const int* in_sizes, int n_in,
                              void* d_out, int out_size, void* d_ws, size_t ws_size,
                              hipStream_t stream) {
    const float* nrm = (const float*)d_in[0];   // (256,128,3) f32
    const float* W   = (const float*)d_in[1];   // (16,8,5) f32
    float* out = (float*)d_out;                 // (256,) f32
    float* ws  = (float*)d_ws;                  // >= 2048 f32 scratch

    plane_kernel<<<dim3(256 * NCH), dim3(1024), 0, stream>>>(nrm, W, ws);
    finish_kernel<<<dim3(1), dim3(256), 0, stream>>>(ws, out);
}